// Round 16
// baseline (125.832 us; speedup 1.0000x reference)
//
#include <hip/hip_runtime.h>
#include <hip/hip_bf16.h>

#define NROWS 8192      // B*T
#define KDIM  768       // F_IN
#define VSZ   320       // V
#define GSZ   2         // G
#define NCOL  640       // G*V
#define DSZ   128       // D
#define BM    64        // rows per gemm block
#define NMT   (NROWS / BM)             // 128 M-tiles
#define NBLK  (NMT * 2)                // 256 gemm blocks = 1/CU
#define NKB   24                       // K blocks of 32 (prep layout)
#define XQ_TOTAL (NROWS * GSZ * DSZ)   // 2097152
#define MARGIN 1.5f     // bf16-stored-logit margin (r6-proven: quant 0.75 + gemm err)
#define XBLKS 3072                     // prep blocks for x
#define WBLKS 240                      // prep blocks for W
#define EPIBLK 1024                    // epi blocks (8 rows each)

typedef __attribute__((ext_vector_type(8))) short bf16x8;
typedef __attribute__((ext_vector_type(4))) float f32x4;

static __device__ __forceinline__ short f2bf(float f) {
    union { __hip_bfloat16 h; short s; } u;
    u.h = __float2bfloat16(f);   // round-to-nearest-even
    return u.s;
}

static __device__ __forceinline__ void gload_lds16(const void* g, void* l) {
    __builtin_amdgcn_global_load_lds(
        (const __attribute__((address_space(1))) void*)g,
        (__attribute__((address_space(3))) void*)l, 16, 0, 0);
}

// ---------------- prep: pack x and W to frag-major bf16 ----------------
__global__ __launch_bounds__(256) void prep_k(const float* __restrict__ x,
                                              const float* __restrict__ W,
                                              short* __restrict__ Xb,
                                              short* __restrict__ Wb) {
    const int bid = blockIdx.x;
    const float* src;
    short* dst;
    int id, row, k;
    if (bid < XBLKS) {
        id = bid * 256 + threadIdx.x;           // 0..786431
        const int lane = id & 63;
        const int f    = id >> 6;               // 0..12287
        const int rblk = f / NKB;
        const int kb   = f - rblk * NKB;
        row = rblk * 16 + (lane & 15);
        k   = kb * 32 + (lane >> 4) * 8;
        src = x; dst = Xb;
    } else {
        id = (bid - XBLKS) * 256 + threadIdx.x; // 0..61439
        const int lane = id & 63;
        const int f    = id >> 6;               // 0..959
        const int n    = f % 5;
        const int t2   = f / 5;
        const int hc   = t2 & 7;
        const int kb   = t2 >> 3;               // 0..23
        row = (hc * 5 + n) * 16 + (lane & 15);  // W col
        k   = kb * 32 + (lane >> 4) * 8;
        src = W; dst = Wb;
    }
    const float4 a = *(const float4*)(src + (size_t)row * KDIM + k);
    const float4 c = *(const float4*)(src + (size_t)row * KDIM + k + 4);
    bf16x8 r;
    r[0] = f2bf(a.x); r[1] = f2bf(a.y); r[2] = f2bf(a.z); r[3] = f2bf(a.w);
    r[4] = f2bf(c.x); r[5] = f2bf(c.y); r[6] = f2bf(c.z); r[7] = f2bf(c.w);
    *(bf16x8*)(dst + (size_t)id * 8) = r;
}

// Per K-step (64 k) stage: 48 frags = 8 A (f<8) + 40 B; wave w (of 16) issues
// f = w, w+16, w+32 (exactly 3 -> uniform vmcnt(3)). Frag f at byte f*1024.
#define STAGE(kb64, BUF) do {                                                  \
    _Pragma("unroll")                                                          \
    for (int j = 0; j < 3; ++j) {                                              \
        const int f = w + 16 * j;                                              \
        const short* src;                                                      \
        if (f < 8) {                                                           \
            src = Xb + ((size_t)(mt * 4 + (f >> 1)) * 24 + (2 * (kb64) + (f & 1))) * 512; \
        } else {                                                               \
            const int i = f - 8;                                               \
            const int kf = i / 20, rm = i % 20;                                \
            src = Wb + ((size_t)((2 * (kb64) + kf) * 8 + hc0 + rm / 5) * 5 + rm % 5) * 512; \
        }                                                                      \
        gload_lds16(src + lane * 8, (char*)(BUF) + f * 1024);                  \
    }                                                                          \
} while (0)

#define COMPUTE(BUF) do {                                                      \
    const char* _bp = (const char*)(BUF);                                      \
    const bf16x8 a0 = *(const bf16x8*)(_bp + (rs * 2 + 0) * 1024 + lane * 16); \
    const bf16x8 a1 = *(const bf16x8*)(_bp + (rs * 2 + 1) * 1024 + lane * 16); \
    bf16x8 b0_[5], b1_[5];                                                     \
    _Pragma("unroll")                                                          \
    for (int n = 0; n < 5; ++n) {                                              \
        b0_[n] = *(const bf16x8*)(_bp + 8192 + (cc * 5 + n) * 1024 + lane * 16);      \
        b1_[n] = *(const bf16x8*)(_bp + 8192 + (20 + cc * 5 + n) * 1024 + lane * 16); \
    }                                                                          \
    _Pragma("unroll")                                                          \
    for (int n = 0; n < 5; ++n)                                                \
        acc[n] = __builtin_amdgcn_mfma_f32_16x16x32_bf16(a0, b0_[n], acc[n], 0, 0, 0); \
    _Pragma("unroll")                                                          \
    for (int n = 0; n < 5; ++n)                                                \
        acc[n] = __builtin_amdgcn_mfma_f32_16x16x32_bf16(a1, b1_[n], acc[n], 0, 0, 0); \
} while (0)

#define SYNCN do {                                                             \
    asm volatile("s_waitcnt vmcnt(3)" ::: "memory");                           \
    __builtin_amdgcn_sched_barrier(0);                                         \
    __builtin_amdgcn_s_barrier();                                              \
} while (0)
#define SYNC0 do {                                                             \
    asm volatile("s_waitcnt vmcnt(0)" ::: "memory");                           \
    __builtin_amdgcn_sched_barrier(0);                                         \
    __builtin_amdgcn_s_barrier();                                              \
} while (0)

// ---------------- GEMM: 16-wave LDS-staged pipeline (r12 loop) + bf16 logit store ----------------
__global__ __launch_bounds__(1024, 4) void gemm_k(
    const short* __restrict__ Xb, const short* __restrict__ Wb,
    const float* __restrict__ b, unsigned short* __restrict__ lg) {

    __shared__ __align__(16) char bufs[3][48 * 1024];   // 147,456 B

    const int tid  = threadIdx.x;
    const int lane = tid & 63;
    const int w    = tid >> 6;       // wave 0..15
    const int l15  = lane & 15;
    const int l4   = lane >> 4;
    const int sb   = ((int)blockIdx.x & 7) * (NBLK / 8) + ((int)blockIdx.x >> 3);
    const int mt   = sb >> 1;
    const int h    = sb & 1;         // group
    const int row0 = mt * BM;
    const int rs   = w >> 2;         // row-set 0..3 (16 rows each)
    const int cc   = w & 3;          // col-chunk 0..3 (80 cols)
    const int rbase = rs * 16;
    const int hc0  = h * 4;
    const int nf0  = h * 20 + cc * 5;

    char* B0 = bufs[0];
    char* B1 = bufs[1];
    char* B2 = bufs[2];

    f32x4 acc[5];
#pragma unroll
    for (int n = 0; n < 5; ++n) acc[n] = (f32x4){0.f, 0.f, 0.f, 0.f};

    STAGE(0, B0);
    STAGE(1, B1);
    __syncthreads();

#pragma unroll 1
    for (int t = 0; t < 3; ++t) {
        const int kb = 3 * t;
        STAGE(kb + 2, B2); COMPUTE(B0); SYNCN;
        STAGE(kb + 3, B0); COMPUTE(B1); SYNCN;
        STAGE(kb + 4, B1); COMPUTE(B2); SYNCN;
    }
    STAGE(11, B2); COMPUTE(B0); SYNCN;
    COMPUTE(B1); SYNC0;
    COMPUTE(B2);

    // bias + store bf16 logits
#pragma unroll
    for (int n = 0; n < 5; ++n) {
        const int col = (nf0 + n) * 16 + l15;
        const float bv = b[col];
#pragma unroll
        for (int r = 0; r < 4; ++r) {
            const int row = row0 + rbase + l4 * 4 + r;
            lg[(size_t)row * NCOL + col] = (unsigned short)f2bf(acc[n][r] + bv);
        }
    }
}

// ---------------- epilogue: high-TLP, wave-owns-row, ballot-based candidates ----------------
// grid 1024 x 512 thr = 8 waves; block owns rows [bid*8, +8); wave w owns row bid*8+w
// (both groups). 4 blocks/CU -> 32 waves/CU. No cross-wave combines; no global atomics.
__global__ __launch_bounds__(512) void epi_k(
    const unsigned short* __restrict__ lg, const float* __restrict__ x,
    const float* __restrict__ W, const float* __restrict__ b,
    const float* __restrict__ codebook,
    float* __restrict__ partials,   // [EPIBLK][1280]: counts(640) then probs(640)
    float* __restrict__ xq) {

    __shared__ float pacc[NCOL];
    __shared__ float cnt_f[NCOL];
    __shared__ int   code_s[8][2];

    const int tid  = threadIdx.x;
    const int lane = tid & 63;
    const int w    = tid >> 6;       // wave 0..7
    const int grow = (int)blockIdx.x * 8 + w;

    for (int i = tid; i < NCOL; i += 512) { pacc[i] = 0.f; cnt_f[i] = 0.f; }
    __syncthreads();

    float preg[2][5];

#pragma unroll
    for (int g = 0; g < 2; ++g) {
        float l[5];
#pragma unroll
        for (int q = 0; q < 5; ++q) {
            const unsigned short v = lg[(size_t)grow * NCOL + g * VSZ + lane + 64 * q];
            l[q] = __uint_as_float((unsigned)v << 16);
        }
        // lane-local max
        float m = l[0]; int amq = 0;
#pragma unroll
        for (int q = 1; q < 5; ++q) if (l[q] > m) { m = l[q]; amq = q; }
        int acol = g * VSZ + lane + 64 * amq;
        // wave reduce (max, lowest-col tie-break)
#pragma unroll
        for (int off = 32; off >= 1; off >>= 1) {
            const float om = __shfl_xor(m, off);
            const int   oc = __shfl_xor(acol, off);
            if (om > m || (om == m && oc < acol)) { m = om; acol = oc; }
        }
        // candidates via ballot
        unsigned long long mask[5];
        int total = 0;
#pragma unroll
        for (int q = 0; q < 5; ++q) {
            mask[q] = __ballot(l[q] > m - MARGIN);
            total += __popcll(mask[q]);
        }
        // softmax
        float s = 0.f;
#pragma unroll
        for (int q = 0; q < 5; ++q) { l[q] = __expf(l[q] - m); s += l[q]; }
#pragma unroll
        for (int off = 32; off >= 1; off >>= 1) s += __shfl_xor(s, off);
        const float inv = 1.f / s;
#pragma unroll
        for (int q = 0; q < 5; ++q) preg[g][q] = l[q] * inv;

        int code = acol;
        if (total > 1) {
            // fp32-exact refinement over all candidates (whole wave per dot)
            float bestv = -3.4e38f; int bestc = 0x7fffffff;
#pragma unroll 1
            for (int q = 0; q < 5; ++q) {
                unsigned long long mm = mask[q];
                while (mm) {
                    const int bit = __ffsll((long long)mm) - 1;
                    mm &= mm - 1;
                    const int col = g * VSZ + bit + 64 * q;
                    float p = 0.f;
                    for (int j = lane; j < KDIM; j += 64)
                        p += x[(size_t)grow * KDIM + j] * W[(size_t)col * KDIM + j];
#pragma unroll
                    for (int off = 32; off >= 1; off >>= 1) p += __shfl_xor(p, off);
                    p += b[col];
                    if (p > bestv || (p == bestv && col < bestc)) { bestv = p; bestc = col; }
                }
            }
            code = bestc;
        }
        if (lane == 0) code_s[w][g] = code;
    }
    __syncthreads();

    // counts histogram + prob column sums (LDS atomics)
    if (tid < 16) atomicAdd(&cnt_f[code_s[tid >> 1][tid & 1]], 1.f);
#pragma unroll
    for (int g = 0; g < 2; ++g)
#pragma unroll
        for (int q = 0; q < 5; ++q)
            atomicAdd(&pacc[g * VSZ + lane + 64 * q], preg[g][q]);

    // gather xq: 8 rows x 256 floats = 512 float4, one per thread
    {
        const int row = tid >> 6;           // 0..7
        const int c   = tid & 63;
        const int gg  = c >> 5;
        const int d4  = (c & 31) * 4;
        const int k   = code_s[row][gg];
        const float4 v = *(const float4*)(codebook + (size_t)k * DSZ + d4);
        *(float4*)(xq + (size_t)((int)blockIdx.x * 8 + row) * (GSZ * DSZ) + gg * DSZ + d4) = v;
    }
    __syncthreads();

    // per-block partials (plain coalesced stores)
    float* myp = partials + (size_t)blockIdx.x * (2 * NCOL);
    for (int i = tid; i < 2 * NCOL; i += 512)
        myp[i] = (i < NCOL) ? cnt_f[i] : pacc[i - NCOL];
}

// ---------------- reduce partials ----------------
__global__ __launch_bounds__(256) void reduce_k(const float* __restrict__ partials,
                                                float* __restrict__ accf) {
    const int c = blockIdx.x * 256 + threadIdx.x;   // 0..1279
    float s = 0.f;
#pragma unroll 8
    for (int m = 0; m < EPIBLK; ++m) s += partials[(size_t)m * (2 * NCOL) + c];
    accf[c] = s;
}

// ---------------- perplexities + constant ----------------
__global__ __launch_bounds__(640) void finalize_k(const float* __restrict__ accf,
                                                  float* __restrict__ out_scalars) {
    __shared__ float se_c[GSZ], se_p[GSZ];
    const int t = threadIdx.x;
    if (t < GSZ) { se_c[t] = 0.f; se_p[t] = 0.f; }
    __syncthreads();
    const int g = t / VSZ;
    const float hp = accf[t]        * (1.f / (float)NROWS);
    const float ap = accf[NCOL + t] * (1.f / (float)NROWS);
    float tc = hp * logf(hp + 1e-7f);
    float tp = ap * logf(ap + 1e-7f);
#pragma unroll
    for (int off = 32; off >= 1; off >>= 1) {
        tc += __shfl_xor(tc, off);
        tp += __shfl_xor(tp, off);
    }
    if ((t & 63) == 0) { atomicAdd(&se_c[g], tc); atomicAdd(&se_p[g], tp); }
    __syncthreads();
    if (t == 0) {
        out_scalars[0] = (float)NCOL;
        out_scalars[1] = expf(-se_c[0]) + expf(-se_c[1]);
        out_scalars[2] = expf(-se_p[0]) + expf(-se_p[1]);
    }
}

extern "C" void kernel_launch(void* const* d_in, const int* in_sizes, int n_in,
                              void* d_out, int out_size, void* d_ws, size_t ws_size,
                              hipStream_t stream) {
    const float* x        = (const float*)d_in[0];
    const float* W        = (const float*)d_in[1];
    const float* b        = (const float*)d_in[2];
    const float* codebook = (const float*)d_in[3];
    float* out = (float*)d_out;

    char* ws = (char*)d_ws;
    short*          Wb = (short*)ws;                          //   983,040 B
    short*          Xb = (short*)(ws + 983040);               // 12,582,912 B (gemm-only)
    unsigned short* lg = (unsigned short*)(ws + 13565952);    // 10,485,760 B -> 24,051,712
    // partials/accf overlay the Xb region (epi runs after gemm completes; stream-ordered)
    float* partials = (float*)(ws + 983040);                  // 1024*1280*4 = 5,242,880 B
    float* accf     = (float*)(ws + 983040 + 5242880);        //     5,120 B

    prep_k<<<dim3(XBLKS + WBLKS), dim3(256), 0, stream>>>(x, W, Xb, Wb);
    gemm_k<<<dim3(NBLK), dim3(1024), 0, stream>>>(Xb, Wb, b, lg);
    epi_k<<<dim3(EPIBLK), dim3(512), 0, stream>>>(lg, x, W, b, codebook, partials, out);
    reduce_k<<<dim3(5), dim3(256), 0, stream>>>(partials, accf);
    finalize_k<<<dim3(1), dim3(640), 0, stream>>>(accf, out + XQ_TOTAL);
}

// Round 17
// 113.140 us; speedup vs baseline: 1.1122x; 1.1122x over previous
//
#include <hip/hip_runtime.h>
#include <hip/hip_bf16.h>

#define NROWS 8192      // B*T
#define KDIM  768       // F_IN
#define VSZ   320       // V
#define GSZ   2         // G
#define NCOL  640       // G*V
#define DSZ   128       // D
#define BM    64        // rows per block
#define NMT   (NROWS / BM)             // 128 M-tiles
#define NBLK  (NMT * 2)                // 256 blocks (x2 group-halves) = 1/CU
#define NKB   24                       // K blocks of 32 (prep layout)
#define XQ_TOTAL (NROWS * GSZ * DSZ)   // 2097152
#define MARGIN 0.75f    // 12 sigma of bf16-dot pairwise error (sigma ~0.062)
#define XBLKS 3072                     // prep blocks for x
#define WBLKS 240                      // prep blocks for W

typedef __attribute__((ext_vector_type(8))) short bf16x8;
typedef __attribute__((ext_vector_type(4))) float f32x4;

static __device__ __forceinline__ short f2bf(float f) {
    union { __hip_bfloat16 h; short s; } u;
    u.h = __float2bfloat16(f);   // round-to-nearest-even
    return u.s;
}

static __device__ __forceinline__ void gload_lds16(const void* g, void* l) {
    __builtin_amdgcn_global_load_lds(
        (const __attribute__((address_space(1))) void*)g,
        (__attribute__((address_space(3))) void*)l, 16, 0, 0);
}

// ---------------- prep: pack x and W to frag-major bf16; zero accf + counter ----------------
__global__ __launch_bounds__(256) void prep_k(const float* __restrict__ x,
                                              const float* __restrict__ W,
                                              short* __restrict__ Xb,
                                              short* __restrict__ Wb,
                                              float* __restrict__ accf) {
    const int bid = blockIdx.x;
    if (bid == 0) {
        for (int i = threadIdx.x; i < 2 * NCOL + 1; i += 256) accf[i] = 0.f;  // +counter
    }
    const float* src;
    short* dst;
    int id, row, k;
    if (bid < XBLKS) {
        id = bid * 256 + threadIdx.x;           // 0..786431
        const int lane = id & 63;
        const int f    = id >> 6;               // 0..12287
        const int rblk = f / NKB;
        const int kb   = f - rblk * NKB;
        row = rblk * 16 + (lane & 15);
        k   = kb * 32 + (lane >> 4) * 8;
        src = x; dst = Xb;
    } else {
        id = (bid - XBLKS) * 256 + threadIdx.x; // 0..61439
        const int lane = id & 63;
        const int f    = id >> 6;               // 0..959
        const int n    = f % 5;
        const int t2   = f / 5;
        const int hc   = t2 & 7;
        const int kb   = t2 >> 3;               // 0..23
        row = (hc * 5 + n) * 16 + (lane & 15);  // W col
        k   = kb * 32 + (lane >> 4) * 8;
        src = W; dst = Wb;
    }
    const float4 a = *(const float4*)(src + (size_t)row * KDIM + k);
    const float4 c = *(const float4*)(src + (size_t)row * KDIM + k + 4);
    bf16x8 r;
    r[0] = f2bf(a.x); r[1] = f2bf(a.y); r[2] = f2bf(a.z); r[3] = f2bf(a.w);
    r[4] = f2bf(c.x); r[5] = f2bf(c.y); r[6] = f2bf(c.z); r[7] = f2bf(c.w);
    *(bf16x8*)(dst + (size_t)id * 8) = r;
}

// Per K-step (64 k) stage: 48 frags = 8 A (f<8) + 40 B; wave w (of 16) issues
// f = w, w+16, w+32 (exactly 3 -> uniform vmcnt(3)). Frag f at byte f*1024.
#define STAGE(kb64, BUF) do {                                                  \
    _Pragma("unroll")                                                          \
    for (int j = 0; j < 3; ++j) {                                              \
        const int f = w + 16 * j;                                              \
        const short* src;                                                      \
        if (f < 8) {                                                           \
            src = Xb + ((size_t)(mt * 4 + (f >> 1)) * 24 + (2 * (kb64) + (f & 1))) * 512; \
        } else {                                                               \
            const int i = f - 8;                                               \
            const int kf = i / 20, rm = i % 20;                                \
            src = Wb + ((size_t)((2 * (kb64) + kf) * 8 + hc0 + rm / 5) * 5 + rm % 5) * 512; \
        }                                                                      \
        gload_lds16(src + lane * 8, (char*)(BUF) + f * 1024);                  \
    }                                                                          \
} while (0)

#define COMPUTE(BUF) do {                                                      \
    const char* _bp = (const char*)(BUF);                                      \
    const bf16x8 a0 = *(const bf16x8*)(_bp + (rs * 2 + 0) * 1024 + lane * 16); \
    const bf16x8 a1 = *(const bf16x8*)(_bp + (rs * 2 + 1) * 1024 + lane * 16); \
    bf16x8 b0_[5], b1_[5];                                                     \
    _Pragma("unroll")                                                          \
    for (int n = 0; n < 5; ++n) {                                              \
        b0_[n] = *(const bf16x8*)(_bp + 8192 + (cc * 5 + n) * 1024 + lane * 16);      \
        b1_[n] = *(const bf16x8*)(_bp + 8192 + (20 + cc * 5 + n) * 1024 + lane * 16); \
    }                                                                          \
    _Pragma("unroll")                                                          \
    for (int n = 0; n < 5; ++n)                                                \
        acc[n] = __builtin_amdgcn_mfma_f32_16x16x32_bf16(a0, b0_[n], acc[n], 0, 0, 0); \
    _Pragma("unroll")                                                          \
    for (int n = 0; n < 5; ++n)                                                \
        acc[n] = __builtin_amdgcn_mfma_f32_16x16x32_bf16(a1, b1_[n], acc[n], 0, 0, 0); \
} while (0)

#define SYNCN do {                                                             \
    asm volatile("s_waitcnt vmcnt(3)" ::: "memory");                           \
    __builtin_amdgcn_sched_barrier(0);                                         \
    __builtin_amdgcn_s_barrier();                                              \
} while (0)
#define SYNC0 do {                                                             \
    asm volatile("s_waitcnt vmcnt(0)" ::: "memory");                           \
    __builtin_amdgcn_sched_barrier(0);                                         \
    __builtin_amdgcn_s_barrier();                                              \
} while (0)

// ---------------- fused: 16-wave LDS-staged MFMA GEMM + epilogue + last-block finalize ----------------
// grid 256 = 128 M-tiles x 2 group-halves (XCD-swizzled); 1024 threads = 16 waves (rs x cc).
__global__ __launch_bounds__(1024, 4) void fused_vq_k(
    const short* __restrict__ Xb, const short* __restrict__ Wb,
    const float* __restrict__ x, const float* __restrict__ W,
    const float* __restrict__ b, const float* __restrict__ codebook,
    float* __restrict__ accf, float* __restrict__ xq,
    float* __restrict__ out_scalars) {

    __shared__ __align__(16) char bufs[3][48 * 1024];   // 147,456 B
    __shared__ float pacc[4][VSZ];
    __shared__ float cnt_f[VSZ];
    __shared__ float wmax[BM][4];
    __shared__ int   warg[BM][4];
    __shared__ float ssum[BM][4];
    __shared__ float rmax_s[BM];
    __shared__ int   rarg_s[BM];
    __shared__ int   cnt_s[BM];
    __shared__ int   list_s[BM][16];
    __shared__ int   code_s[BM];
    __shared__ int   work_s[BM];
    __shared__ int   nwork_s;
    __shared__ int   last_s;
    __shared__ float se_c2[GSZ], se_p2[GSZ];

    const int tid   = threadIdx.x;
    const int lane  = tid & 63;
    const int w     = tid >> 6;       // wave 0..15
    const int l15   = lane & 15;
    const int l4    = lane >> 4;
    const int sb    = ((int)blockIdx.x & 7) * (NBLK / 8) + ((int)blockIdx.x >> 3);
    const int mt    = sb >> 1;
    const int h     = sb & 1;         // group
    const int row0  = mt * BM;
    const int rs    = w >> 2;         // row-set 0..3 (16 rows each)
    const int cc    = w & 3;          // col-chunk 0..3 (80 cols)
    const int rbase = rs * 16;
    const int hc0   = h * 4;
    const int nf0   = h * 20 + cc * 5;

    for (int i = tid; i < VSZ; i += 1024) cnt_f[i] = 0.f;
    if (tid < BM) cnt_s[tid] = 0;
    if (tid == 0) nwork_s = 0;

    char* B0 = bufs[0];
    char* B1 = bufs[1];
    char* B2 = bufs[2];

    f32x4 acc[5];
#pragma unroll
    for (int n = 0; n < 5; ++n) acc[n] = (f32x4){0.f, 0.f, 0.f, 0.f};

    STAGE(0, B0);
    STAGE(1, B1);
    __syncthreads();

#pragma unroll 1
    for (int t = 0; t < 3; ++t) {
        const int kb = 3 * t;
        STAGE(kb + 2, B2); COMPUTE(B0); SYNCN;
        STAGE(kb + 3, B0); COMPUTE(B1); SYNCN;
        STAGE(kb + 4, B1); COMPUTE(B2); SYNCN;
    }
    STAGE(11, B2); COMPUTE(B0); SYNCN;
    COMPUTE(B1); SYNC0;
    COMPUTE(B2);

    // bias (zeros in this problem, kept exact)
#pragma unroll
    for (int n = 0; n < 5; ++n) {
        const float bv = b[(nf0 + n) * 16 + l15];
#pragma unroll
        for (int r = 0; r < 4; ++r) acc[n][r] += bv;
    }

    // E1: wave-local per-row max/argmax (rows rbase+l4*4+r, cols (nf0+n)*16+l15)
    float m4[4]; int a4[4];
#pragma unroll
    for (int r = 0; r < 4; ++r) { m4[r] = -3.4e38f; a4[r] = 0x7fffffff; }
#pragma unroll
    for (int n = 0; n < 5; ++n) {
        const int col = (nf0 + n) * 16 + l15;
#pragma unroll
        for (int r = 0; r < 4; ++r) {
            const float v = acc[n][r];
            if (v > m4[r]) { m4[r] = v; a4[r] = col; }
        }
    }
#pragma unroll
    for (int off = 8; off >= 1; off >>= 1)
#pragma unroll
        for (int r = 0; r < 4; ++r) {
            const float om = __shfl_xor(m4[r], off);
            const int   oa = __shfl_xor(a4[r], off);
            if (om > m4[r] || (om == m4[r] && oa < a4[r])) { m4[r] = om; a4[r] = oa; }
        }
    if (l15 == 0)
#pragma unroll
        for (int r = 0; r < 4; ++r) {
            const int row = rbase + l4 * 4 + r;
            wmax[row][cc] = m4[r];
            warg[row][cc] = a4[r];
        }
    __syncthreads();

    // E2a: combine 4 col-chunks -> row max over 320
    if (tid < BM) {
        float m = -3.4e38f; int c = 0x7fffffff;
#pragma unroll
        for (int q = 0; q < 4; ++q) {
            const float mq = wmax[tid][q];
            const int   cq = warg[tid][q];
            if (mq > m || (mq == m && cq < c)) { m = mq; c = cq; }
        }
        rmax_s[tid] = m;
        rarg_s[tid] = c;
    }
    __syncthreads();

    // E2b: candidate scan + exp + denominator partials
    float rm[4];
#pragma unroll
    for (int r = 0; r < 4; ++r) rm[r] = rmax_s[rbase + l4 * 4 + r];
    float sden[4] = {0.f, 0.f, 0.f, 0.f};
#pragma unroll
    for (int n = 0; n < 5; ++n) {
        const int col = (nf0 + n) * 16 + l15;
#pragma unroll
        for (int r = 0; r < 4; ++r) {
            const float v = acc[n][r];
            if (v > rm[r] - MARGIN) {
                const int row = rbase + l4 * 4 + r;
                const int idx = atomicAdd(&cnt_s[row], 1);
                if (idx < 16) list_s[row][idx] = col;
            }
            const float e = __expf(v - rm[r]);
            acc[n][r] = e;
            sden[r] += e;
        }
    }
#pragma unroll
    for (int off = 8; off >= 1; off >>= 1)
#pragma unroll
        for (int r = 0; r < 4; ++r) sden[r] += __shfl_xor(sden[r], off);
    if (l15 == 0)
#pragma unroll
        for (int r = 0; r < 4; ++r) ssum[rbase + l4 * 4 + r][cc] = sden[r];
    __syncthreads();

    // E3: single-candidate fast path; multi-candidate -> worklist
    if (tid < BM) {
        if (cnt_s[tid] <= 1) {
            code_s[tid] = rarg_s[tid];
        } else {
            const int wi = atomicAdd(&nwork_s, 1);
            work_s[wi] = tid;
        }
    }

    // E5: softmax column sums -> pacc[rs][v] (plain stores, disjoint (rs,cc) slots)
    float inv[4];
#pragma unroll
    for (int r = 0; r < 4; ++r) {
        const int row = rbase + l4 * 4 + r;
        inv[r] = 1.f / (ssum[row][0] + ssum[row][1] + ssum[row][2] + ssum[row][3]);
    }
#pragma unroll
    for (int n = 0; n < 5; ++n) {
        float pc = 0.f;
#pragma unroll
        for (int r = 0; r < 4; ++r) pc += acc[n][r] * inv[r];
        pc += __shfl_xor(pc, 16);
        pc += __shfl_xor(pc, 32);
        if (l4 == 0) pacc[rs][(nf0 + n) * 16 + l15 - h * VSZ] = pc;
    }
    __syncthreads();

    // E4: fp32-exact refinement, one wave per pending row (float4 + unrolled: 3
    // concurrent 16B loads per lane instead of 12 dependent-latency scalar loads)
    const int nwork = nwork_s;
    for (int it = w; it < nwork; it += 16) {
        const int row  = work_s[it];
        const int grow = row0 + row;
        const int nc   = min(cnt_s[row], 16);
        const float4* xr = (const float4*)(x + (size_t)grow * KDIM);
        float bestv = -3.4e38f; int bestc = 0x7fffffff;
        for (int ci = 0; ci < nc; ++ci) {
            const int col = list_s[row][ci];
            const float4* wr = (const float4*)(W + (size_t)col * KDIM);
            float p = 0.f;
#pragma unroll
            for (int j = 0; j < 3; ++j) {
                const float4 xv = xr[lane + 64 * j];
                const float4 wv = wr[lane + 64 * j];
                p += xv.x * wv.x + xv.y * wv.y + xv.z * wv.z + xv.w * wv.w;
            }
#pragma unroll
            for (int off = 32; off >= 1; off >>= 1) p += __shfl_xor(p, off);
            p += b[col];
            if (p > bestv || (p == bestv && col < bestc)) { bestv = p; bestc = col; }
        }
        if (lane == 0) code_s[row] = bestc;
    }
    __syncthreads();

    // counts histogram in LDS
    if (tid < BM) atomicAdd(&cnt_f[code_s[tid] - h * VSZ], 1.f);

    // E7: gather xq for this block's 64 rows, its group's 128-dim half
#pragma unroll
    for (int u = 0; u < 2; ++u) {
        const int f   = tid + u * 1024;     // float4 index 0..2047
        const int row = f >> 5;
        const int d4  = (f & 31) * 4;
        const int k   = code_s[row];        // global col = codebook row
        const float4 v = *(const float4*)(codebook + (size_t)k * DSZ + d4);
        *(float4*)(xq + (size_t)(row0 + row) * (GSZ * DSZ) + h * DSZ + d4) = v;
    }
    __syncthreads();

    // flush block-local sums with global atomics
    for (int i = tid; i < VSZ; i += 1024) {
        atomicAdd(&accf[h * VSZ + i], cnt_f[i]);
        atomicAdd(&accf[NCOL + h * VSZ + i],
                  pacc[0][i] + pacc[1][i] + pacc[2][i] + pacc[3][i]);
    }

    // ---- last-arriving block computes perplexities (saves a kernel launch) ----
    __threadfence();
    if (tid == 0)
        last_s = (atomicAdd((int*)(accf + 2 * NCOL), 1) == NBLK - 1);
    __syncthreads();
    if (last_s) {
        if (tid < GSZ) { se_c2[tid] = 0.f; se_p2[tid] = 0.f; }
        __syncthreads();
        if (tid < NCOL) {   // 640 = 10 full waves
            const int g2 = tid / VSZ;
            // atomic reads: device-scope coherent across XCDs
            const float hp = atomicAdd(&accf[tid], 0.f)        * (1.f / (float)NROWS);
            const float ap = atomicAdd(&accf[NCOL + tid], 0.f) * (1.f / (float)NROWS);
            float tc = hp * logf(hp + 1e-7f);
            float tp = ap * logf(ap + 1e-7f);
#pragma unroll
            for (int off = 32; off >= 1; off >>= 1) {
                tc += __shfl_xor(tc, off);
                tp += __shfl_xor(tp, off);
            }
            if ((tid & 63) == 0) { atomicAdd(&se_c2[g2], tc); atomicAdd(&se_p2[g2], tp); }
        }
        __syncthreads();
        if (tid == 0) {
            out_scalars[0] = (float)NCOL;
            out_scalars[1] = expf(-se_c2[0]) + expf(-se_c2[1]);
            out_scalars[2] = expf(-se_p2[0]) + expf(-se_p2[1]);
        }
    }
}

extern "C" void kernel_launch(void* const* d_in, const int* in_sizes, int n_in,
                              void* d_out, int out_size, void* d_ws, size_t ws_size,
                              hipStream_t stream) {
    const float* x        = (const float*)d_in[0];
    const float* W        = (const float*)d_in[1];
    const float* b        = (const float*)d_in[2];
    const float* codebook = (const float*)d_in[3];
    float* out = (float*)d_out;

    short* Wb   = (short*)d_ws;                                  //   983,040 B
    short* Xb   = (short*)((char*)d_ws + 983040);                // 12,582,912 B
    float* accf = (float*)((char*)d_ws + 983040 + 12582912);     // 1280 f + counter

    prep_k<<<dim3(XBLKS + WBLKS), dim3(256), 0, stream>>>(x, W, Xb, Wb, accf);
    fused_vq_k<<<dim3(NBLK), dim3(1024), 0, stream>>>(Xb, Wb, x, W, b, codebook,
                                                      accf, out, out + XQ_TOTAL);
}

// Round 18
// 46.333 us; speedup vs baseline: 2.7158x; 2.4419x over previous
//
#include <hip/hip_runtime.h>
#include <hip/hip_bf16.h>

#define NROWS 8192      // B*T
#define KDIM  768       // F_IN
#define VSZ   320       // V
#define GSZ   2         // G
#define NCOL  640       // G*V
#define DSZ   128       // D
#define BM    64        // rows per block
#define NMT   (NROWS / BM)             // 128 M-tiles
#define NBLK  (NMT * 2)                // 256 blocks (x2 group-halves)
#define NKB   24                       // K blocks of 32
#define XQ_TOTAL (NROWS * GSZ * DSZ)   // 2097152
#define MARGIN 0.75f    // 12 sigma of bf16-dot pairwise error (sigma ~0.062)
#define XBLKS 3072                     // prep blocks for x
#define WBLKS 240                      // prep blocks for W

typedef __attribute__((ext_vector_type(8))) short bf16x8;
typedef __attribute__((ext_vector_type(4))) float f32x4;

static __device__ __forceinline__ short f2bf(float f) {
    union { __hip_bfloat16 h; short s; } u;
    u.h = __float2bfloat16(f);   // round-to-nearest-even
    return u.s;
}

static __device__ __forceinline__ void gload_lds16(const void* g, void* l) {
    __builtin_amdgcn_global_load_lds(
        (const __attribute__((address_space(1))) void*)g,
        (__attribute__((address_space(3))) void*)l, 16, 0, 0);
}

// ---------------- prep: pack x and W to frag-major bf16; zero accf ----------------
__global__ __launch_bounds__(256) void prep_k(const float* __restrict__ x,
                                              const float* __restrict__ W,
                                              short* __restrict__ Xb,
                                              short* __restrict__ Wb,
                                              float* __restrict__ accf) {
    const int bid = blockIdx.x;
    if (bid == 0) {
        for (int i = threadIdx.x; i < 2 * NCOL; i += 256) accf[i] = 0.f;
    }
    const float* src;
    short* dst;
    int id, row, k;
    if (bid < XBLKS) {
        id = bid * 256 + threadIdx.x;           // 0..786431
        const int lane = id & 63;
        const int f    = id >> 6;               // 0..12287
        const int rblk = f / NKB;
        const int kb   = f - rblk * NKB;
        row = rblk * 16 + (lane & 15);
        k   = kb * 32 + (lane >> 4) * 8;
        src = x; dst = Xb;
    } else {
        id = (bid - XBLKS) * 256 + threadIdx.x; // 0..61439
        const int lane = id & 63;
        const int f    = id >> 6;               // 0..959
        const int n    = f % 5;
        const int t2   = f / 5;
        const int hc   = t2 & 7;
        const int kb   = t2 >> 3;               // 0..23
        row = (hc * 5 + n) * 16 + (lane & 15);  // W col
        k   = kb * 32 + (lane >> 4) * 8;
        src = W; dst = Wb;
    }
    const float4 a = *(const float4*)(src + (size_t)row * KDIM + k);
    const float4 c = *(const float4*)(src + (size_t)row * KDIM + k + 4);
    bf16x8 r;
    r[0] = f2bf(a.x); r[1] = f2bf(a.y); r[2] = f2bf(a.z); r[3] = f2bf(a.w);
    r[4] = f2bf(c.x); r[5] = f2bf(c.y); r[6] = f2bf(c.z); r[7] = f2bf(c.w);
    *(bf16x8*)(dst + (size_t)id * 8) = r;
}

// Per 32-k step stage: 24 frags = 4 A (f<4, 16 rows each) + 20 B; wave w (of 8)
// issues f = w, w+8, w+16 (exactly 3 -> uniform vmcnt(3)). Frag f at byte f*1024.
#define STAGE(kb32, BUF) do {                                                  \
    _Pragma("unroll")                                                          \
    for (int j = 0; j < 3; ++j) {                                              \
        const int f = w + 8 * j;                                               \
        const short* src;                                                      \
        if (f < 4) {                                                           \
            src = Xb + ((size_t)(mt * 4 + f) * 24 + (kb32)) * 512;             \
        } else {                                                               \
            const int rm = f - 4;                                              \
            src = Wb + ((size_t)((kb32) * 8 + hc0 + rm / 5) * 5 + rm % 5) * 512; \
        }                                                                      \
        gload_lds16(src + lane * 8, (char*)(BUF) + f * 1024);                  \
    }                                                                          \
} while (0)

// Wave tile 32x80: acc[hh][n]; reads 2 A + 5 B frags, 10 MFMA per 32-k step.
#define COMPUTE(BUF) do {                                                      \
    const char* _bp = (const char*)(BUF);                                      \
    const bf16x8 a0 = *(const bf16x8*)(_bp + (rs * 2 + 0) * 1024 + lane * 16); \
    const bf16x8 a1 = *(const bf16x8*)(_bp + (rs * 2 + 1) * 1024 + lane * 16); \
    bf16x8 bb[5];                                                              \
    _Pragma("unroll")                                                          \
    for (int n = 0; n < 5; ++n)                                                \
        bb[n] = *(const bf16x8*)(_bp + 4096 + (cc * 5 + n) * 1024 + lane * 16);\
    _Pragma("unroll")                                                          \
    for (int n = 0; n < 5; ++n) {                                              \
        acc[0][n] = __builtin_amdgcn_mfma_f32_16x16x32_bf16(a0, bb[n], acc[0][n], 0, 0, 0); \
        acc[1][n] = __builtin_amdgcn_mfma_f32_16x16x32_bf16(a1, bb[n], acc[1][n], 0, 0, 0); \
    }                                                                          \
} while (0)

#define SYNCN do {                                                             \
    asm volatile("s_waitcnt vmcnt(3)" ::: "memory");                           \
    __builtin_amdgcn_sched_barrier(0);                                         \
    __builtin_amdgcn_s_barrier();                                              \
} while (0)
#define SYNC0 do {                                                             \
    asm volatile("s_waitcnt vmcnt(0)" ::: "memory");                           \
    __builtin_amdgcn_sched_barrier(0);                                         \
    __builtin_amdgcn_s_barrier();                                              \
} while (0)

// ---------------- fused: 8-wave 32x80-tile GEMM, 2 blocks/CU, BK=32 dbuf ----------------
// grid 256 = 128 M-tiles x 2 groups (XCD-swizzled); 512 threads = 8 waves (rs x cc).
// LDS 61.5 KB -> 2 blocks/CU (16 waves/CU); LDS reads/MFMA 0.7 vs r12's 1.2.
__global__ __launch_bounds__(512, 4) void fused_vq_k(
    const short* __restrict__ Xb, const short* __restrict__ Wb,
    const float* __restrict__ x, const float* __restrict__ W,
    const float* __restrict__ b, const float* __restrict__ codebook,
    float* __restrict__ accf, float* __restrict__ xq) {

    __shared__ __align__(16) char bufs[2][24 * 1024];   // 49,152 B
    __shared__ float pacc[2][VSZ];
    __shared__ float cnt_f[VSZ];
    __shared__ float wmax[BM][4];
    __shared__ int   warg[BM][4];
    __shared__ float ssum[BM][4];
    __shared__ float rmax_s[BM];
    __shared__ int   rarg_s[BM];
    __shared__ int   cnt_s[BM];
    __shared__ int   list_s[BM][16];
    __shared__ int   code_s[BM];
    __shared__ int   work_s[BM];
    __shared__ int   nwork_s;

    const int tid   = threadIdx.x;
    const int lane  = tid & 63;
    const int w     = tid >> 6;       // wave 0..7
    const int l15   = lane & 15;
    const int l4    = lane >> 4;
    const int sb    = ((int)blockIdx.x & 7) * (NBLK / 8) + ((int)blockIdx.x >> 3);
    const int mt    = sb >> 1;
    const int h     = sb & 1;         // group
    const int row0  = mt * BM;
    const int rs    = w >> 2;         // row-set 0..1 (32 rows each)
    const int cc    = w & 3;          // col-chunk 0..3 (80 cols)
    const int hc0   = h * 4;
    const int nf0   = h * 20 + cc * 5;

    for (int i = tid; i < VSZ; i += 512) cnt_f[i] = 0.f;
    if (tid < BM) cnt_s[tid] = 0;
    if (tid == 0) nwork_s = 0;

    char* B0 = bufs[0];
    char* B1 = bufs[1];

    f32x4 acc[2][5];
#pragma unroll
    for (int hh = 0; hh < 2; ++hh)
#pragma unroll
        for (int n = 0; n < 5; ++n) acc[hh][n] = (f32x4){0.f, 0.f, 0.f, 0.f};

    STAGE(0, B0);
    __syncthreads();    // compiler drains vmcnt before barrier: B0 ready

#pragma unroll 1
    for (int t = 0; t < 11; ++t) {
        STAGE(2 * t + 1, B1); COMPUTE(B0); SYNCN;
        STAGE(2 * t + 2, B0); COMPUTE(B1); SYNCN;
    }
    STAGE(23, B1); COMPUTE(B0); SYNC0;
    COMPUTE(B1);

    // bias (zeros in this problem, kept exact)
#pragma unroll
    for (int n = 0; n < 5; ++n) {
        const float bv = b[(nf0 + n) * 16 + l15];
#pragma unroll
        for (int hh = 0; hh < 2; ++hh)
#pragma unroll
            for (int r = 0; r < 4; ++r) acc[hh][n][r] += bv;
    }

    // E1: wave-local per-row max/argmax; rows rs*32 + hh*16 + l4*4 + r
    float m4[2][4]; int a4[2][4];
#pragma unroll
    for (int hh = 0; hh < 2; ++hh)
#pragma unroll
        for (int r = 0; r < 4; ++r) { m4[hh][r] = -3.4e38f; a4[hh][r] = 0x7fffffff; }
#pragma unroll
    for (int n = 0; n < 5; ++n) {
        const int col = (nf0 + n) * 16 + l15;
#pragma unroll
        for (int hh = 0; hh < 2; ++hh)
#pragma unroll
            for (int r = 0; r < 4; ++r) {
                const float v = acc[hh][n][r];
                if (v > m4[hh][r]) { m4[hh][r] = v; a4[hh][r] = col; }
            }
    }
#pragma unroll
    for (int off = 8; off >= 1; off >>= 1)
#pragma unroll
        for (int hh = 0; hh < 2; ++hh)
#pragma unroll
            for (int r = 0; r < 4; ++r) {
                const float om = __shfl_xor(m4[hh][r], off);
                const int   oa = __shfl_xor(a4[hh][r], off);
                if (om > m4[hh][r] || (om == m4[hh][r] && oa < a4[hh][r])) {
                    m4[hh][r] = om; a4[hh][r] = oa;
                }
            }
    if (l15 == 0)
#pragma unroll
        for (int hh = 0; hh < 2; ++hh)
#pragma unroll
            for (int r = 0; r < 4; ++r) {
                const int row = rs * 32 + hh * 16 + l4 * 4 + r;
                wmax[row][cc] = m4[hh][r];
                warg[row][cc] = a4[hh][r];
            }
    __syncthreads();

    // E2a: combine 4 col-chunks -> row max over 320
    if (tid < BM) {
        float m = -3.4e38f; int c = 0x7fffffff;
#pragma unroll
        for (int q = 0; q < 4; ++q) {
            const float mq = wmax[tid][q];
            const int   cq = warg[tid][q];
            if (mq > m || (mq == m && cq < c)) { m = mq; c = cq; }
        }
        rmax_s[tid] = m;
        rarg_s[tid] = c;
    }
    __syncthreads();

    // E2b: candidate scan + exp + denominator partials
    float rm[2][4];
#pragma unroll
    for (int hh = 0; hh < 2; ++hh)
#pragma unroll
        for (int r = 0; r < 4; ++r) rm[hh][r] = rmax_s[rs * 32 + hh * 16 + l4 * 4 + r];
    float sden[2][4] = {{0.f,0.f,0.f,0.f},{0.f,0.f,0.f,0.f}};
#pragma unroll
    for (int n = 0; n < 5; ++n) {
        const int col = (nf0 + n) * 16 + l15;
#pragma unroll
        for (int hh = 0; hh < 2; ++hh)
#pragma unroll
            for (int r = 0; r < 4; ++r) {
                const float v = acc[hh][n][r];
                if (v > rm[hh][r] - MARGIN) {
                    const int row = rs * 32 + hh * 16 + l4 * 4 + r;
                    const int idx = atomicAdd(&cnt_s[row], 1);
                    if (idx < 16) list_s[row][idx] = col;
                }
                const float e = __expf(v - rm[hh][r]);
                acc[hh][n][r] = e;
                sden[hh][r] += e;
            }
    }
#pragma unroll
    for (int off = 8; off >= 1; off >>= 1)
#pragma unroll
        for (int hh = 0; hh < 2; ++hh)
#pragma unroll
            for (int r = 0; r < 4; ++r) sden[hh][r] += __shfl_xor(sden[hh][r], off);
    if (l15 == 0)
#pragma unroll
        for (int hh = 0; hh < 2; ++hh)
#pragma unroll
            for (int r = 0; r < 4; ++r)
                ssum[rs * 32 + hh * 16 + l4 * 4 + r][cc] = sden[hh][r];
    __syncthreads();

    // E3: single-candidate fast path; multi-candidate -> worklist
    if (tid < BM) {
        if (cnt_s[tid] <= 1) {
            code_s[tid] = rarg_s[tid];
        } else {
            const int wi = atomicAdd(&nwork_s, 1);
            work_s[wi] = tid;
        }
    }

    // E5: softmax column sums -> pacc[rs][v] (plain stores, disjoint (rs,cc) slots)
    float inv[2][4];
#pragma unroll
    for (int hh = 0; hh < 2; ++hh)
#pragma unroll
        for (int r = 0; r < 4; ++r) {
            const int row = rs * 32 + hh * 16 + l4 * 4 + r;
            inv[hh][r] = 1.f / (ssum[row][0] + ssum[row][1] + ssum[row][2] + ssum[row][3]);
        }
#pragma unroll
    for (int n = 0; n < 5; ++n) {
        float pc = 0.f;
#pragma unroll
        for (int hh = 0; hh < 2; ++hh)
#pragma unroll
            for (int r = 0; r < 4; ++r) pc += acc[hh][n][r] * inv[hh][r];
        pc += __shfl_xor(pc, 16);
        pc += __shfl_xor(pc, 32);
        if (l4 == 0) pacc[rs][(nf0 + n) * 16 + l15 - h * VSZ] = pc;
    }
    __syncthreads();

    // E4: fp32-exact refinement, one wave per pending row (float4, unrolled)
    const int nwork = nwork_s;
    for (int it = w; it < nwork; it += 8) {
        const int row  = work_s[it];
        const int grow = row0 + row;
        const int nc   = min(cnt_s[row], 16);
        const float4* xr = (const float4*)(x + (size_t)grow * KDIM);
        float bestv = -3.4e38f; int bestc = 0x7fffffff;
        for (int ci = 0; ci < nc; ++ci) {
            const int col = list_s[row][ci];
            const float4* wr = (const float4*)(W + (size_t)col * KDIM);
            float p = 0.f;
#pragma unroll
            for (int j = 0; j < 3; ++j) {
                const float4 xv = xr[lane + 64 * j];
                const float4 wv = wr[lane + 64 * j];
                p += xv.x * wv.x + xv.y * wv.y + xv.z * wv.z + xv.w * wv.w;
            }
#pragma unroll
            for (int off = 32; off >= 1; off >>= 1) p += __shfl_xor(p, off);
            p += b[col];
            if (p > bestv || (p == bestv && col < bestc)) { bestv = p; bestc = col; }
        }
        if (lane == 0) code_s[row] = bestc;
    }
    __syncthreads();

    // counts histogram in LDS
    if (tid < BM) atomicAdd(&cnt_f[code_s[tid] - h * VSZ], 1.f);

    // E7: gather xq for this block's 64 rows, its group's 128-dim half
#pragma unroll
    for (int u = 0; u < 4; ++u) {
        const int f   = tid + u * 512;      // float4 index 0..2047
        const int row = f >> 5;
        const int d4  = (f & 31) * 4;
        const int k   = code_s[row];        // global col = codebook row
        const float4 v = *(const float4*)(codebook + (size_t)k * DSZ + d4);
        *(float4*)(xq + (size_t)(row0 + row) * (GSZ * DSZ) + h * DSZ + d4) = v;
    }
    __syncthreads();

    // flush block-local sums with global atomics
    for (int i = tid; i < VSZ; i += 512) {
        atomicAdd(&accf[h * VSZ + i], cnt_f[i]);
        atomicAdd(&accf[NCOL + h * VSZ + i], pacc[0][i] + pacc[1][i]);
    }
}

// ---------------- perplexities + constant ----------------
__global__ __launch_bounds__(640) void finalize_k(const float* __restrict__ accf,
                                                  float* __restrict__ out_scalars) {
    __shared__ float se_c[GSZ], se_p[GSZ];
    const int t = threadIdx.x;
    if (t < GSZ) { se_c[t] = 0.f; se_p[t] = 0.f; }
    __syncthreads();
    const int g = t / VSZ;
    const float hp = accf[t]        * (1.f / (float)NROWS);
    const float ap = accf[NCOL + t] * (1.f / (float)NROWS);
    float tc = hp * logf(hp + 1e-7f);
    float tp = ap * logf(ap + 1e-7f);
#pragma unroll
    for (int off = 32; off >= 1; off >>= 1) {
        tc += __shfl_xor(tc, off);
        tp += __shfl_xor(tp, off);
    }
    if ((t & 63) == 0) { atomicAdd(&se_c[g], tc); atomicAdd(&se_p[g], tp); }
    __syncthreads();
    if (t == 0) {
        out_scalars[0] = (float)NCOL;
        out_scalars[1] = expf(-se_c[0]) + expf(-se_c[1]);
        out_scalars[2] = expf(-se_p[0]) + expf(-se_p[1]);
    }
}

extern "C" void kernel_launch(void* const* d_in, const int* in_sizes, int n_in,
                              void* d_out, int out_size, void* d_ws, size_t ws_size,
                              hipStream_t stream) {
    const float* x        = (const float*)d_in[0];
    const float* W        = (const float*)d_in[1];
    const float* b        = (const float*)d_in[2];
    const float* codebook = (const float*)d_in[3];
    float* out = (float*)d_out;

    short* Wb   = (short*)d_ws;                                  //   983,040 B
    short* Xb   = (short*)((char*)d_ws + 983040);                // 12,582,912 B
    float* accf = (float*)((char*)d_ws + 983040 + 12582912);     //     5,120 B

    prep_k<<<dim3(XBLKS + WBLKS), dim3(256), 0, stream>>>(x, W, Xb, Wb, accf);
    fused_vq_k<<<dim3(NBLK), dim3(512), 0, stream>>>(Xb, Wb, x, W, b, codebook,
                                                     accf, out);
    finalize_k<<<dim3(1), dim3(640), 0, stream>>>(accf, out + XQ_TOTAL);
}

// Round 19
// 45.167 us; speedup vs baseline: 2.7860x; 1.0258x over previous
//
#include <hip/hip_runtime.h>
#include <hip/hip_bf16.h>

#define NROWS 8192      // B*T
#define KDIM  768       // F_IN
#define VSZ   320       // V
#define GSZ   2         // G
#define NCOL  640       // G*V
#define DSZ   128       // D
#define BM    64        // rows per block
#define NMT   (NROWS / BM)             // 128 M-tiles
#define NBLK  (NMT * 2)                // 256 blocks (x2 group-halves)
#define NKB   24                       // K blocks of 32
#define XQ_TOTAL (NROWS * GSZ * DSZ)   // 2097152
#define MARGIN 0.75f    // 12 sigma of bf16-dot pairwise error (sigma ~0.062)

typedef __attribute__((ext_vector_type(8))) short bf16x8;
typedef __attribute__((ext_vector_type(4))) float f32x4;

static __device__ __forceinline__ short f2bf(float f) {
    union { __hip_bfloat16 h; short s; } u;
    u.h = __float2bfloat16(f);   // round-to-nearest-even
    return u.s;
}

static __device__ __forceinline__ void gload_lds16(const void* g, void* l) {
    __builtin_amdgcn_global_load_lds(
        (const __attribute__((address_space(1))) void*)g,
        (__attribute__((address_space(3))) void*)l, 16, 0, 0);
}

// ---------------- prep: pack W only (frag-major bf16); zero accf ----------------
// Wb frag fid = (kb*8 + hc)*5 + n (hc 0..7, n 0..4): col = (hc*5+n)*16 + (l&15),
// k = kb*32 + (l>>4)*8, 8 bf16 at byte lane*16.
__global__ __launch_bounds__(256) void prep_w_k(const float* __restrict__ W,
                                                short* __restrict__ Wb,
                                                float* __restrict__ accf) {
    if (blockIdx.x == 0) {
        for (int i = threadIdx.x; i < 2 * NCOL; i += 256) accf[i] = 0.f;
    }
    const int id   = blockIdx.x * 256 + threadIdx.x;   // 0..61439
    const int lane = id & 63;
    const int f    = id >> 6;                           // 0..959
    const int n    = f % 5;
    const int t2   = f / 5;
    const int hc   = t2 & 7;
    const int kb   = t2 >> 3;                           // 0..23
    const int col  = (hc * 5 + n) * 16 + (lane & 15);
    const int k    = kb * 32 + (lane >> 4) * 8;
    const float4 a = *(const float4*)(W + (size_t)col * KDIM + k);
    const float4 c = *(const float4*)(W + (size_t)col * KDIM + k + 4);
    bf16x8 r;
    r[0] = f2bf(a.x); r[1] = f2bf(a.y); r[2] = f2bf(a.z); r[3] = f2bf(a.w);
    r[4] = f2bf(c.x); r[5] = f2bf(c.y); r[6] = f2bf(c.z); r[7] = f2bf(c.w);
    *(bf16x8*)(Wb + (size_t)id * 8) = r;
}

// B staging for one 32-k step: 20 frags; each of 8 waves issues 3 gloads (uniform
// vmcnt); frags 16..19 are double-issued (identical data -> benign).
#define STAGEB(kb32, BUF) do {                                                 \
    _Pragma("unroll")                                                          \
    for (int j = 0; j < 3; ++j) {                                              \
        const int rm = (j == 0) ? w : (j == 1) ? (w + 8) : (16 + (w & 3));     \
        const short* srcp = Wb + ((size_t)((kb32) * 8 + hc0 + rm / 5) * 5 + rm % 5) * 512; \
        gload_lds16(srcp + lane * 8, (char*)(BUF) + 4096 + rm * 1024);         \
    }                                                                          \
} while (0)

// A staging: thread owns (row = tid>>3, kk = (tid&7)*4); converts float4 -> 4 bf16
// and ds_writes 8B into frag layout (frag row>>4; byte ((row&15)+16*(kk>>3))*16 + (kk&4)*2).
#define AWRITE(BUF, v) do {                                                    \
    const short s0 = f2bf((v).x), s1 = f2bf((v).y);                            \
    const short s2 = f2bf((v).z), s3 = f2bf((v).w);                            \
    const int lo = (s0 & 0xffff) | ((int)s1 << 16);                            \
    const int hi = (s2 & 0xffff) | ((int)s3 << 16);                            \
    *(int2*)((char*)(BUF) + a_off) = make_int2(lo, hi);                        \
} while (0)

// Wave tile 32x80: acc[hh][n]; reads 2 A + 5 B frags, 10 MFMA per 32-k step.
#define COMPUTE(BUF) do {                                                      \
    const char* _bp = (const char*)(BUF);                                      \
    const bf16x8 a0 = *(const bf16x8*)(_bp + (rs * 2 + 0) * 1024 + lane * 16); \
    const bf16x8 a1 = *(const bf16x8*)(_bp + (rs * 2 + 1) * 1024 + lane * 16); \
    bf16x8 bb[5];                                                              \
    _Pragma("unroll")                                                          \
    for (int n = 0; n < 5; ++n)                                                \
        bb[n] = *(const bf16x8*)(_bp + 4096 + (cc * 5 + n) * 1024 + lane * 16);\
    _Pragma("unroll")                                                          \
    for (int n = 0; n < 5; ++n) {                                              \
        acc[0][n] = __builtin_amdgcn_mfma_f32_16x16x32_bf16(a0, bb[n], acc[0][n], 0, 0, 0); \
        acc[1][n] = __builtin_amdgcn_mfma_f32_16x16x32_bf16(a1, bb[n], acc[1][n], 0, 0, 0); \
    }                                                                          \
} while (0)

#define SYNC(N) do {                                                           \
    asm volatile("s_waitcnt vmcnt(" #N ") lgkmcnt(0)" ::: "memory");           \
    __builtin_amdgcn_sched_barrier(0);                                         \
    __builtin_amdgcn_s_barrier();                                              \
} while (0)

// ---------------- fused: in-kernel A-staging GEMM + epilogue (r18 structure) ----------------
// grid 256 = 128 M-tiles x 2 groups (XCD-swizzled); 512 threads = 8 waves (rs x cc);
// 2 blocks/CU. A staged straight from x (f32->bf16 in-kernel), B via global_load_lds
// from packed Wb. No Xb pre-pack kernel.
__global__ __launch_bounds__(512, 4) void fused_vq_k(
    const short* __restrict__ Wb,
    const float* __restrict__ x, const float* __restrict__ W,
    const float* __restrict__ b, const float* __restrict__ codebook,
    float* __restrict__ accf, float* __restrict__ xq) {

    __shared__ __align__(16) char bufs[2][24 * 1024];   // 49,152 B
    __shared__ float pacc[2][VSZ];
    __shared__ float cnt_f[VSZ];
    __shared__ float wmax[BM][4];
    __shared__ int   warg[BM][4];
    __shared__ float ssum[BM][4];
    __shared__ float rmax_s[BM];
    __shared__ int   rarg_s[BM];
    __shared__ int   cnt_s[BM];
    __shared__ int   list_s[BM][16];
    __shared__ int   code_s[BM];
    __shared__ int   work_s[BM];
    __shared__ int   nwork_s;

    const int tid   = threadIdx.x;
    const int lane  = tid & 63;
    const int w     = tid >> 6;       // wave 0..7
    const int l15   = lane & 15;
    const int l4    = lane >> 4;
    const int sb    = ((int)blockIdx.x & 7) * (NBLK / 8) + ((int)blockIdx.x >> 3);
    const int mt    = sb >> 1;
    const int h     = sb & 1;         // group
    const int row0  = mt * BM;
    const int rs    = w >> 2;         // row-set 0..1 (32 rows each)
    const int cc    = w & 3;          // col-chunk 0..3 (80 cols)
    const int hc0   = h * 4;
    const int nf0   = h * 20 + cc * 5;

    // A-staging thread ownership
    const int arow  = tid >> 3;           // 0..63
    const int akk   = (tid & 7) * 4;      // 0,4,..,28
    const int a_off = (arow >> 4) * 1024 + ((arow & 15) + 16 * (akk >> 3)) * 16 + (akk & 4) * 2;
    const float* xrow = x + (size_t)(row0 + arow) * KDIM + akk;

    for (int i = tid; i < VSZ; i += 512) cnt_f[i] = 0.f;
    if (tid < BM) cnt_s[tid] = 0;
    if (tid == 0) nwork_s = 0;

    char* B0 = bufs[0];
    char* B1 = bufs[1];

    f32x4 acc[2][5];
#pragma unroll
    for (int hh = 0; hh < 2; ++hh)
#pragma unroll
        for (int n = 0; n < 5; ++n) acc[hh][n] = (f32x4){0.f, 0.f, 0.f, 0.f};

    // ---- prologue: stage kb=0 into B0; preload x(kb=1) ----
    float4 xv = *(const float4*)(xrow);          // x(kb0)
    AWRITE(B0, xv);                              // compiler waits xv before use
    STAGEB(0, B0);
    xv = *(const float4*)(xrow + 32);            // x(kb1)
    SYNC(1);                                     // Bg(0) done; xv(kb1) may fly

    // ---- main loop: phases k = 0..21 (stage k+1, preload x(k+2), compute k) ----
#pragma unroll 1
    for (int k = 0; k < 22; ++k) {
        char* bufn = bufs[0] + (((k + 1) & 1) * 24576);
        char* bufc = bufs[0] + ((k & 1) * 24576);
        AWRITE(bufn, xv);                        // writes x(k+1)
        STAGEB(k + 1, bufn);
        xv = *(const float4*)(xrow + (k + 2) * 32);
        COMPUTE(bufc);
        SYNC(1);                                 // Bg(k+1) done; x-load may fly
    }
    // phase 22: stage kb23 (xv = x(23)), no preload
    AWRITE(B1, xv);
    STAGEB(23, B1);
    COMPUTE(B0);                                 // kb22
    SYNC(0);
    COMPUTE(B1);                                 // kb23

    // bias (zeros in this problem, kept exact)
#pragma unroll
    for (int n = 0; n < 5; ++n) {
        const float bv = b[(nf0 + n) * 16 + l15];
#pragma unroll
        for (int hh = 0; hh < 2; ++hh)
#pragma unroll
            for (int r = 0; r < 4; ++r) acc[hh][n][r] += bv;
    }

    // E1: wave-local per-row max/argmax; rows rs*32 + hh*16 + l4*4 + r
    float m4[2][4]; int a4[2][4];
#pragma unroll
    for (int hh = 0; hh < 2; ++hh)
#pragma unroll
        for (int r = 0; r < 4; ++r) { m4[hh][r] = -3.4e38f; a4[hh][r] = 0x7fffffff; }
#pragma unroll
    for (int n = 0; n < 5; ++n) {
        const int col = (nf0 + n) * 16 + l15;
#pragma unroll
        for (int hh = 0; hh < 2; ++hh)
#pragma unroll
            for (int r = 0; r < 4; ++r) {
                const float v = acc[hh][n][r];
                if (v > m4[hh][r]) { m4[hh][r] = v; a4[hh][r] = col; }
            }
    }
#pragma unroll
    for (int off = 8; off >= 1; off >>= 1)
#pragma unroll
        for (int hh = 0; hh < 2; ++hh)
#pragma unroll
            for (int r = 0; r < 4; ++r) {
                const float om = __shfl_xor(m4[hh][r], off);
                const int   oa = __shfl_xor(a4[hh][r], off);
                if (om > m4[hh][r] || (om == m4[hh][r] && oa < a4[hh][r])) {
                    m4[hh][r] = om; a4[hh][r] = oa;
                }
            }
    if (l15 == 0)
#pragma unroll
        for (int hh = 0; hh < 2; ++hh)
#pragma unroll
            for (int r = 0; r < 4; ++r) {
                const int row = rs * 32 + hh * 16 + l4 * 4 + r;
                wmax[row][cc] = m4[hh][r];
                warg[row][cc] = a4[hh][r];
            }
    __syncthreads();

    // E2a: combine 4 col-chunks -> row max over 320
    if (tid < BM) {
        float m = -3.4e38f; int c = 0x7fffffff;
#pragma unroll
        for (int q = 0; q < 4; ++q) {
            const float mq = wmax[tid][q];
            const int   cq = warg[tid][q];
            if (mq > m || (mq == m && cq < c)) { m = mq; c = cq; }
        }
        rmax_s[tid] = m;
        rarg_s[tid] = c;
    }
    __syncthreads();

    // E2b: candidate scan + exp + denominator partials
    float rm[2][4];
#pragma unroll
    for (int hh = 0; hh < 2; ++hh)
#pragma unroll
        for (int r = 0; r < 4; ++r) rm[hh][r] = rmax_s[rs * 32 + hh * 16 + l4 * 4 + r];
    float sden[2][4] = {{0.f,0.f,0.f,0.f},{0.f,0.f,0.f,0.f}};
#pragma unroll
    for (int n = 0; n < 5; ++n) {
        const int col = (nf0 + n) * 16 + l15;
#pragma unroll
        for (int hh = 0; hh < 2; ++hh)
#pragma unroll
            for (int r = 0; r < 4; ++r) {
                const float v = acc[hh][n][r];
                if (v > rm[hh][r] - MARGIN) {
                    const int row = rs * 32 + hh * 16 + l4 * 4 + r;
                    const int idx = atomicAdd(&cnt_s[row], 1);
                    if (idx < 16) list_s[row][idx] = col;
                }
                const float e = __expf(v - rm[hh][r]);
                acc[hh][n][r] = e;
                sden[hh][r] += e;
            }
    }
#pragma unroll
    for (int off = 8; off >= 1; off >>= 1)
#pragma unroll
        for (int hh = 0; hh < 2; ++hh)
#pragma unroll
            for (int r = 0; r < 4; ++r) sden[hh][r] += __shfl_xor(sden[hh][r], off);
    if (l15 == 0)
#pragma unroll
        for (int hh = 0; hh < 2; ++hh)
#pragma unroll
            for (int r = 0; r < 4; ++r)
                ssum[rs * 32 + hh * 16 + l4 * 4 + r][cc] = sden[hh][r];
    __syncthreads();

    // E3: single-candidate fast path; multi-candidate -> worklist
    if (tid < BM) {
        if (cnt_s[tid] <= 1) {
            code_s[tid] = rarg_s[tid];
        } else {
            const int wi = atomicAdd(&nwork_s, 1);
            work_s[wi] = tid;
        }
    }

    // E5: softmax column sums -> pacc[rs][v] (plain stores, disjoint (rs,cc) slots)
    float inv[2][4];
#pragma unroll
    for (int hh = 0; hh < 2; ++hh)
#pragma unroll
        for (int r = 0; r < 4; ++r) {
            const int row = rs * 32 + hh * 16 + l4 * 4 + r;
            inv[hh][r] = 1.f / (ssum[row][0] + ssum[row][1] + ssum[row][2] + ssum[row][3]);
        }
#pragma unroll
    for (int n = 0; n < 5; ++n) {
        float pc = 0.f;
#pragma unroll
        for (int hh = 0; hh < 2; ++hh)
#pragma unroll
            for (int r = 0; r < 4; ++r) pc += acc[hh][n][r] * inv[hh][r];
        pc += __shfl_xor(pc, 16);
        pc += __shfl_xor(pc, 32);
        if (l4 == 0) pacc[rs][(nf0 + n) * 16 + l15 - h * VSZ] = pc;
    }
    __syncthreads();

    // E4: fp32-exact refinement, one wave per pending row (float4, unrolled)
    const int nwork = nwork_s;
    for (int it = w; it < nwork; it += 8) {
        const int row  = work_s[it];
        const int grow = row0 + row;
        const int nc   = min(cnt_s[row], 16);
        const float4* xr = (const float4*)(x + (size_t)grow * KDIM);
        float bestv = -3.4e38f; int bestc = 0x7fffffff;
        for (int ci = 0; ci < nc; ++ci) {
            const int col = list_s[row][ci];
            const float4* wr = (const float4*)(W + (size_t)col * KDIM);
            float p = 0.f;
#pragma unroll
            for (int j = 0; j < 3; ++j) {
                const float4 xv2 = xr[lane + 64 * j];
                const float4 wv2 = wr[lane + 64 * j];
                p += xv2.x * wv2.x + xv2.y * wv2.y + xv2.z * wv2.z + xv2.w * wv2.w;
            }
#pragma unroll
            for (int off = 32; off >= 1; off >>= 1) p += __shfl_xor(p, off);
            p += b[col];
            if (p > bestv || (p == bestv && col < bestc)) { bestv = p; bestc = col; }
        }
        if (lane == 0) code_s[row] = bestc;
    }
    __syncthreads();

    // counts histogram in LDS
    if (tid < BM) atomicAdd(&cnt_f[code_s[tid] - h * VSZ], 1.f);

    // E7: gather xq for this block's 64 rows, its group's 128-dim half
#pragma unroll
    for (int u = 0; u < 4; ++u) {
        const int f   = tid + u * 512;      // float4 index 0..2047
        const int row = f >> 5;
        const int d4  = (f & 31) * 4;
        const int k   = code_s[row];        // global col = codebook row
        const float4 v = *(const float4*)(codebook + (size_t)k * DSZ + d4);
        *(float4*)(xq + (size_t)(row0 + row) * (GSZ * DSZ) + h * DSZ + d4) = v;
    }
    __syncthreads();

    // flush block-local sums with global atomics
    for (int i = tid; i < VSZ; i += 512) {
        atomicAdd(&accf[h * VSZ + i], cnt_f[i]);
        atomicAdd(&accf[NCOL + h * VSZ + i], pacc[0][i] + pacc[1][i]);
    }
}

// ---------------- perplexities + constant ----------------
__global__ __launch_bounds__(640) void finalize_k(const float* __restrict__ accf,
                                                  float* __restrict__ out_scalars) {
    __shared__ float se_c[GSZ], se_p[GSZ];
    const int t = threadIdx.x;
    if (t < GSZ) { se_c[t] = 0.f; se_p[t] = 0.f; }
    __syncthreads();
    const int g = t / VSZ;
    const float hp = accf[t]        * (1.f / (float)NROWS);
    const float ap = accf[NCOL + t] * (1.f / (float)NROWS);
    float tc = hp * logf(hp + 1e-7f);
    float tp = ap * logf(ap + 1e-7f);
#pragma unroll
    for (int off = 32; off >= 1; off >>= 1) {
        tc += __shfl_xor(tc, off);
        tp += __shfl_xor(tp, off);
    }
    if ((t & 63) == 0) { atomicAdd(&se_c[g], tc); atomicAdd(&se_p[g], tp); }
    __syncthreads();
    if (t == 0) {
        out_scalars[0] = (float)NCOL;
        out_scalars[1] = expf(-se_c[0]) + expf(-se_c[1]);
        out_scalars[2] = expf(-se_p[0]) + expf(-se_p[1]);
    }
}

extern "C" void kernel_launch(void* const* d_in, const int* in_sizes, int n_in,
                              void* d_out, int out_size, void* d_ws, size_t ws_size,
                              hipStream_t stream) {
    const float* x        = (const float*)d_in[0];
    const float* W        = (const float*)d_in[1];
    const float* b        = (const float*)d_in[2];
    const float* codebook = (const float*)d_in[3];
    float* out = (float*)d_out;

    short* Wb   = (short*)d_ws;                             //   983,040 B
    float* accf = (float*)((char*)d_ws + 983040);           //     5,120 B

    prep_w_k<<<dim3(240), dim3(256), 0, stream>>>(W, Wb, accf);
    fused_vq_k<<<dim3(NBLK), dim3(512), 0, stream>>>(Wb, x, W, b, codebook,
                                                     accf, out);
    finalize_k<<<dim3(1), dim3(640), 0, stream>>>(accf, out + XQ_TOTAL);
}